// Round 20
// baseline (367.996 us; speedup 1.0000x reference)
//
#include <hip/hip_runtime.h>
#include <hip/hip_bf16.h>
#include <stdint.h>

// ---------------------------------------------------------------------------
// ChebConv with attention + per-(t,k) dropout, MI355X bf16 MFMA implementation
// out[b,t,u,o] = relu( sum_k M[t,k] @ x[b,t] @ Theta[k] )   (associativity)
// mask = threefry2x32 partitionable, key(42), bits = x0^x1   (verified R0)
// B=32 T=12 V=1000(pad 1024) F=O=64 K=3
//
// R20: K=3072 single GEMM (R12/R13-verified; kills stage-2 and pacc[3] ->
// pacc[4][4]=64 AGPR) x R18-verified LDS discipline (dbuf, 1 barrier/chunk,
// XOR content swizzle, issue-early reg prefetch) x 64x64 wave tiles (2x the
// arithmetic intensity of R15-R19's 32x64, which was pinned at the data-path
// balance point ~36% across three different operand paths).
// 256 thr / 4 waves (2x2), block 128u x 128n, 2x32KB LDS -> 2 blocks/CU.
// Per-CU-chunk: LDS 1500cy / global ~1100cy / MFMA 1242cy -> ~83% ceiling.
// transpose_x eliminated (build_yt reads x directly).
// ws: M row-major [36][1024][1024] bf16 (75.5MB) | yt [3][12][NR][1024] bf16
//     (full NR=2048: 151MB, total 226.5MB -- R12/R13 single-dispatch timing
//      proves the full path runs; quarter fallback NR=512 kept).
// ---------------------------------------------------------------------------

typedef __attribute__((ext_vector_type(8))) short short8;
typedef __attribute__((ext_vector_type(4))) float f32x4;

__device__ __forceinline__ ushort f2bf(float f) {
  __hip_bfloat16 h = __float2bfloat16(f);
  return *reinterpret_cast<ushort*>(&h);
}

__device__ __forceinline__ short8 cvt8(float4 a, float4 b) {
  short8 r;
  r[0] = (short)f2bf(a.x); r[1] = (short)f2bf(a.y);
  r[2] = (short)f2bf(a.z); r[3] = (short)f2bf(a.w);
  r[4] = (short)f2bf(b.x); r[5] = (short)f2bf(b.y);
  r[6] = (short)f2bf(b.z); r[7] = (short)f2bf(b.w);
  return r;
}

__device__ __forceinline__ void threefry2x32(uint32_t c0, uint32_t c1,
                                             uint32_t& o0, uint32_t& o1) {
  const uint32_t ks0 = 0u;
  const uint32_t ks1 = 42u;
  const uint32_t ks2 = ks0 ^ ks1 ^ 0x1BD11BDAu;
  uint32_t x0 = c0 + ks0;
  uint32_t x1 = c1 + ks1;
#define TFR(r) { x0 += x1; x1 = (x1 << (r)) | (x1 >> (32 - (r))); x1 ^= x0; }
  TFR(13) TFR(15) TFR(26) TFR(6)
  x0 += ks1; x1 += ks2 + 1u;
  TFR(17) TFR(29) TFR(16) TFR(24)
  x0 += ks2; x1 += ks0 + 2u;
  TFR(13) TFR(15) TFR(26) TFR(6)
  x0 += ks0; x1 += ks1 + 3u;
  TFR(17) TFR(29) TFR(16) TFR(24)
  x0 += ks1; x1 += ks2 + 4u;
  TFR(13) TFR(15) TFR(26) TFR(6)
  x0 += ks2; x1 += ks0 + 5u;
#undef TFR
  o0 = x0; o1 = x1;
}

// ---------------------------------------------------------------------------
// Kernel 1: build masked M (bf16) row-major padded [36][1024][1024] (R3-proven)
// ---------------------------------------------------------------------------
__global__ void build_m(const float* __restrict__ Att,
                        const float* __restrict__ cheb,
                        ushort* __restrict__ Mws) {
  const uint32_t idx = blockIdx.x * 256u + threadIdx.x;
  const uint32_t vp = idx & 1023u;
  const uint32_t up = (idx >> 10) & 1023u;
  const uint32_t tk = idx >> 20;
  float val = 0.f;
  if ((vp < 1000u) & (up < 1000u)) {
    const uint32_t flat = (tk * 1000u + up) * 1000u + vp;
    uint32_t o0, o1;
    threefry2x32(0u, flat, o0, o1);
    const uint32_t bits = o0 ^ o1;
    const float u = __uint_as_float((bits >> 9) | 0x3f800000u) - 1.0f;
    if (u < 0.4f) {
      val = cheb[(tk % 3u) * 1000000u + up * 1000u + vp] *
            Att[up * 1000u + vp] * 2.5f;
    }
  }
  Mws[idx] = f2bf(val);
}

// ---------------------------------------------------------------------------
// Kernel 2: build_yt -- y_k[b,t] = x[b,t] @ Theta_k, stored transposed
// row-major: yt[k][t][nrow=(b-bq0)*64+o][v pad 1024] bf16. (R13-verified)
// 192 thr (3 waves), wave w <-> k=w; 8 vc per block.
// ---------------------------------------------------------------------------
#define MFMA(a, b, c) __builtin_amdgcn_mfma_f32_16x16x32_bf16((a), (b), (c), 0, 0, 0)

__global__ __launch_bounds__(192, 1)
void build_yt(const float* __restrict__ x, const float* __restrict__ Theta,
              ushort* __restrict__ yt, int NR, int bq0) {
  __shared__ __align__(16) ushort sm[27648];  // sTh [0,13824) | sY [13824,..)
  const int tid = threadIdx.x, lane = tid & 63, w = tid >> 6;
  const int quad = lane >> 4, l15 = lane & 15;
  const int vh = blockIdx.x, t = blockIdx.y, bb = blockIdx.z;
  const int b = bq0 + bb;

  for (int e = tid; e < 12288; e += 192) {
    const int k = e >> 12, rem = e & 4095, f = rem >> 6, o = rem & 63;
    sm[k * 4608 + o * 72 + f] = f2bf(Theta[e]);
  }
  __syncthreads();

  const ushort* sTh = sm + w * 4608;
  ushort* sY = sm + 13824 + w * 4608;
  const float* xb = x + (((size_t)b * 12 + t) * 1000) * 64;
  const int seg = lane & 7;

#pragma unroll 1
  for (int vi = 0; vi < 8; ++vi) {
    const int vc = vh * 8 + vi;
    const int v0 = vc * 64;

    f32x4 pacc[4][4];
#pragma unroll
    for (int i = 0; i < 4; ++i)
#pragma unroll
      for (int j = 0; j < 4; ++j) pacc[i][j] = f32x4{0.f, 0.f, 0.f, 0.f};

#pragma unroll
    for (int ks = 0; ks < 2; ++ks) {
      short8 av[4], bv[4];
#pragma unroll
      for (int mi = 0; mi < 4; ++mi)
        av[mi] = *(const short8*)&sTh[(mi * 16 + l15) * 72 + ks * 32 + quad * 8];
#pragma unroll
      for (int ni = 0; ni < 4; ++ni) {
        const int v = v0 + ni * 16 + l15;
        float4 c0 = make_float4(0.f, 0.f, 0.f, 0.f);
        float4 c1 = make_float4(0.f, 0.f, 0.f, 0.f);
        if (v < 1000) {
          const float* row = xb + (size_t)v * 64 + ks * 32 + quad * 8;
          c0 = *(const float4*)row;
          c1 = *(const float4*)(row + 4);
        }
        bv[ni] = cvt8(c0, c1);
      }
#pragma unroll
      for (int mi = 0; mi < 4; ++mi)
#pragma unroll
        for (int ni = 0; ni < 4; ++ni)
          pacc[mi][ni] = MFMA(av[mi], bv[ni], pacc[mi][ni]);
    }

#pragma unroll
    for (int mi = 0; mi < 4; ++mi)
#pragma unroll
      for (int ni = 0; ni < 4; ++ni)
#pragma unroll
        for (int r = 0; r < 4; ++r)
          sY[(mi * 16 + quad * 4 + r) * 72 + ni * 16 + l15] = f2bf(pacc[mi][ni][r]);

#pragma unroll
    for (int p = 0; p < 8; ++p) {
      const int o = p * 8 + (lane >> 3);
      const uint4 val = *(const uint4*)&sY[o * 72 + seg * 8];
      *(uint4*)(yt + (((size_t)(w * 12 + t) * (size_t)NR + (size_t)bb * 64 + o) << 10)
                   + v0 + seg * 8) = val;
    }
  }
}

// ---------------------------------------------------------------------------
// Kernel 3: K=3072 GEMM.  256 thr (4 waves, 2x2), block 128u x 128n per t,
// wave tile 64x64.  48 chunks of K=64 (chunk c: k-slab = c>>4, vc = c&15).
// LDS buffer = A[128][64] (16KB) + B[128][64] (16KB) = 32KB; dbuf 64KB ->
// 2 blocks/CU.  8 named-reg 16B loads/thread/chunk, issue-early, ONE
// __syncthreads per chunk (write targets buffer read last iteration).
// Content XOR-swizzle (verified R3): LDS[r][c16B] = G[r][c ^ (r&7)].
// Epilogue: relu + f32 store straight from pacc (no stage-2).
// Grid XCD-bijective, ut-fastest (8 ut-blocks share B panel in L2).
// ---------------------------------------------------------------------------
#define LOADCH(C)                                                             \
  do {                                                                        \
    const size_t koA_ = ((size_t)((C) >> 4) << 20) + (size_t)(((C) & 15) * 64); \
    const size_t koB_ = (size_t)((C) >> 4) * ytk + (size_t)(((C) & 15) * 64); \
    q0 = *(const uint4*)(Mws + aS0 + koA_);                                   \
    q1 = *(const uint4*)(Mws + aS1 + koA_);                                   \
    q2 = *(const uint4*)(Mws + aS2 + koA_);                                   \
    q3 = *(const uint4*)(Mws + aS3 + koA_);                                   \
    q4 = *(const uint4*)(yt + bS0 + koB_);                                    \
    q5 = *(const uint4*)(yt + bS1 + koB_);                                    \
    q6 = *(const uint4*)(yt + bS2 + koB_);                                    \
    q7 = *(const uint4*)(yt + bS3 + koB_);                                    \
  } while (0)

#define WRITECH(BP)                                                           \
  do {                                                                        \
    *(uint4*)&(BP)[(tid) * 8]               = q0;                             \
    *(uint4*)&(BP)[(256 + tid) * 8]         = q1;                             \
    *(uint4*)&(BP)[(512 + tid) * 8]         = q2;                             \
    *(uint4*)&(BP)[(768 + tid) * 8]         = q3;                             \
    *(uint4*)&(BP)[8192 + (tid) * 8]        = q4;                             \
    *(uint4*)&(BP)[8192 + (256 + tid) * 8]  = q5;                             \
    *(uint4*)&(BP)[8192 + (512 + tid) * 8]  = q6;                             \
    *(uint4*)&(BP)[8192 + (768 + tid) * 8]  = q7;                             \
  } while (0)

#define BURST(BP)                                                             \
  do {                                                                        \
    _Pragma("unroll")                                                         \
    for (int ks = 0; ks < 2; ++ks) {                                          \
      const int cs_ = (((ks * 4 + quad) ^ rsw)) << 3;                         \
      short8 av[4], bv[4];                                                    \
      _Pragma("unroll")                                                       \
      for (int mi = 0; mi < 4; ++mi)                                          \
        av[mi] = *(const short8*)&(BP)[(wr * 64 + mi * 16 + l15) * 64 + cs_]; \
      _Pragma("unroll")                                                       \
      for (int ni = 0; ni < 4; ++ni)                                          \
        bv[ni] = *(const short8*)&(BP)[8192 +                                 \
                     (wc * 64 + ni * 16 + l15) * 64 + cs_];                   \
      _Pragma("unroll")                                                       \
      for (int mi = 0; mi < 4; ++mi)                                          \
        _Pragma("unroll")                                                     \
        for (int ni = 0; ni < 4; ++ni)                                        \
          pacc[mi][ni] = MFMA(av[mi], bv[ni], pacc[mi][ni]);                  \
    }                                                                         \
  } while (0)

__global__ __launch_bounds__(256, 2)
void gemm_main(const ushort* __restrict__ Mws, const ushort* __restrict__ yt,
               float* __restrict__ out, int NR, int bq0, int ntcnt) {
  __shared__ __align__(16) ushort smem[32768];  // 64KB: buf0 | buf1 (16384 ea)
  const int tid = threadIdx.x, lane = tid & 63, w = tid >> 6;
  const int wr = w >> 1, wc = w & 1;            // 2x2 wave grid, tile 64x64
  const int quad = lane >> 4, l15 = lane & 15, rsw = l15 & 7;

  ushort* buf0 = smem;
  ushort* buf1 = smem + 16384;

  // XCD-bijective decode (gridDim.x % 8 == 0), ut-fastest per XCD chunk
  const int nb = (int)gridDim.x;
  const int swz = ((int)blockIdx.x & 7) * (nb >> 3) + ((int)blockIdx.x >> 3);
  const int ut = swz & 7;              // 8 u-tiles of 128
  const int g = swz >> 3;
  const int nt = g % ntcnt;
  const int t = g / ntcnt;
  const int u0 = ut * 128, n0 = nt * 128;

  // staging geometry: slot s = i*256+tid covers row s>>3, 16B-chunk s&7;
  // source chunk = chunk ^ (row&7) (content XOR pre-swizzle, R3-verified)
  const size_t mbase = (size_t)(t * 3) << 20;
  const size_t ytk = (size_t)12 * (size_t)NR * 1024;   // yt k-slab stride
  const int r0 = tid >> 3,         c0s = (tid & 7) ^ (r0 & 7);
  const int r1 = (256 + tid) >> 3, c1s = (tid & 7) ^ (r1 & 7);
  const int r2 = (512 + tid) >> 3, c2s = (tid & 7) ^ (r2 & 7);
  const int r3 = (768 + tid) >> 3, c3s = (tid & 7) ^ (r3 & 7);
  const size_t aS0 = mbase + ((size_t)(u0 + r0) << 10) + c0s * 8;
  const size_t aS1 = mbase + ((size_t)(u0 + r1) << 10) + c1s * 8;
  const size_t aS2 = mbase + ((size_t)(u0 + r2) << 10) + c2s * 8;
  const size_t aS3 = mbase + ((size_t)(u0 + r3) << 10) + c3s * 8;
  const size_t bbase = ((size_t)t * (size_t)NR + n0) << 10;
  const size_t bS0 = bbase + ((size_t)r0 << 10) + c0s * 8;
  const size_t bS1 = bbase + ((size_t)r1 << 10) + c1s * 8;
  const size_t bS2 = bbase + ((size_t)r2 << 10) + c2s * 8;
  const size_t bS3 = bbase + ((size_t)r3 << 10) + c3s * 8;

  f32x4 pacc[4][4];
#pragma unroll
  for (int i = 0; i < 4; ++i)
#pragma unroll
    for (int j = 0; j < 4; ++j) pacc[i][j] = f32x4{0.f, 0.f, 0.f, 0.f};

  uint4 q0, q1, q2, q3, q4, q5, q6, q7;

  // prologue: chunk 0 -> buf0
  LOADCH(0);
  WRITECH(buf0);
  __syncthreads();

  // main K loop: 48 chunks, unrolled x2 for static buffer pointers;
  // one barrier per chunk (write targets the buffer read last iteration)
#pragma unroll 1
  for (int it = 0; it < 24; ++it) {
    const int c = it * 2;
    // even chunk: read buf0; prefetch c+1 -> regs; commit -> buf1
    if (c < 47) LOADCH(c + 1);
    __builtin_amdgcn_s_setprio(1);
    BURST(buf0);
    __builtin_amdgcn_s_setprio(0);
    if (c < 47) WRITECH(buf1);
    __syncthreads();
    // odd chunk: read buf1; prefetch c+2 -> regs; commit -> buf0
    if (c + 1 < 47) LOADCH(c + 2);
    __builtin_amdgcn_s_setprio(1);
    BURST(buf1);
    __builtin_amdgcn_s_setprio(0);
    if (c + 1 < 47) WRITECH(buf0);
    __syncthreads();
  }

  // epilogue: relu + f32 store (no stage-2 -- K=3072 already summed k)
#pragma unroll
  for (int mi = 0; mi < 4; ++mi) {
    const int u_base = u0 + wr * 64 + mi * 16 + quad * 4;
#pragma unroll
    for (int ni = 0; ni < 4; ++ni) {
      const int n = n0 + wc * 64 + ni * 16 + l15;
      const int b = bq0 + (n >> 6), o = n & 63;
      float* op = out + (((size_t)b * 12 + t) * 1000) * 64 + o;
#pragma unroll
      for (int r = 0; r < 4; ++r) {
        const int u = u_base + r;
        if (u < 1000) op[(size_t)u * 64] = fmaxf(pacc[mi][ni][r], 0.f);
      }
    }
  }
}

// ---------------------------------------------------------------------------
extern "C" void kernel_launch(void* const* d_in, const int* in_sizes, int n_in,
                              void* d_out, int out_size, void* d_ws, size_t ws_size,
                              hipStream_t stream) {
  const float* x     = (const float*)d_in[0];
  const float* Att   = (const float*)d_in[1];
  const float* cheb  = (const float*)d_in[2];
  const float* Theta = (const float*)d_in[3];
  float* out = (float*)d_out;

  ushort* Mws = (ushort*)d_ws;           // 75.5 MB row-major padded M
  ushort* yt  = Mws + 37748736ull;       // yt region

  build_m<<<147456, 256, 0, stream>>>(Att, cheb, Mws);

  if (ws_size >= 226492416ull) {
    // full path: yt [3][12][2048][1024] bf16 (151MB)
    build_yt<<<dim3(2, 12, 32), 192, 0, stream>>>(x, Theta, yt, 2048, 0);
    // grid = 12t x 16nt x 8ut = 1536
    gemm_main<<<1536, 256, 0, stream>>>(Mws, yt, out, 2048, 0, 16);
  } else {
    // quarter path: 4 passes of 8 batches; yt [3][12][512][1024] (37.7MB)
    for (int qq = 0; qq < 4; ++qq) {
      build_yt<<<dim3(2, 12, 8), 192, 0, stream>>>(x, Theta, yt, 512, qq * 8);
      gemm_main<<<384, 256, 0, stream>>>(Mws, yt, out, 512, qq * 8, 4);
    }
  }
}